// Round 12
// baseline (215.399 us; speedup 1.0000x reference)
//
#include <hip/hip_runtime.h>

#define B_ 32
#define T_ 2048
#define N_ 128
#define K_ 5
#define BN_ (B_ * N_)
#define PMAX_ 512
#define MINP_ 2

static constexpr double PI_D = 3.14159265358979323846264338327950288;
static constexpr float  S2_F = 0.70710678118654752440f;  // sqrt(1/2)

typedef float vf4 __attribute__((ext_vector_type(4)));

struct cf { float r, i; };

__device__ __forceinline__ void bf_w(cf& u, cf& v, float wr, float wi) {
    const float tr = v.r * wr - v.i * wi;
    const float ti = v.r * wi + v.i * wr;
    v.r = u.r - tr; v.i = u.i - ti;
    u.r += tr;      u.i += ti;
}
__device__ __forceinline__ void bf_1(cf& u, cf& v) {        // w = 1
    const float tr = v.r, ti = v.i;
    v.r = u.r - tr; v.i = u.i - ti;
    u.r += tr;      u.i += ti;
}
__device__ __forceinline__ void bf_mi(cf& u, cf& v) {       // w = -i
    const float tr = v.i, ti = -v.r;
    v.r = u.r - tr; v.i = u.i - ti;
    u.r += tr;      u.i += ti;
}
// LDS bank swizzle: keeps every hot access pattern low-way on 32 banks.
__device__ __forceinline__ int sw(int i) { return i ^ ((i >> 5) & 31); }

// Swap lane-bit L with one reg-bit across a register pair (a=low, b=high).
// Moves value at (laneBitL, regBit) to (regBit, laneBitL). Pure data
// movement: bitwise-identical values, no LDS, no barrier.
__device__ __forceinline__ void xsw1(float& a, float& b, int tid, int L) {
    const float snd = (tid & L) ? a : b;
    const float got = __shfl_xor(snd, L, 64);
    if (tid & L) a = got; else b = got;
}
// One full stage: swap lane-bit L with reg-bit R over cf E[8] (re & im).
#define XSTAGE(L, P0a, P0b, P1a, P1b, P2a, P2b, P3a, P3b)                      \
    xsw1(E[P0a].r, E[P0b].r, tid, (L)); xsw1(E[P0a].i, E[P0b].i, tid, (L));    \
    xsw1(E[P1a].r, E[P1b].r, tid, (L)); xsw1(E[P1a].i, E[P1b].i, tid, (L));    \
    xsw1(E[P2a].r, E[P2b].r, tid, (L)); xsw1(E[P2a].i, E[P2b].i, tid, (L));    \
    xsw1(E[P3a].r, E[P3b].r, tid, (L)); xsw1(E[P3a].i, E[P3b].i, tid, (L));

// ---------------------------------------------------------------------------
// Kernel 0: twiddle table tw[m] = exp(-2*pi*i*m/2048) as float2, into d_ws.
// ---------------------------------------------------------------------------
__global__ __launch_bounds__(256) void pt_twiddle(float2* __restrict__ tw) {
    const int m = blockIdx.x * 256 + threadIdx.x;
    if (m < 1024) {
        double s, c;
        sincos(-2.0 * PI_D * (double)m / 2048.0, &s, &c);
        tw[m] = make_float2((float)c, (float)s);
    }
}

// ---------------------------------------------------------------------------
// v12 = v11 (session best, 214.8) + FUSED mag phase:
//  - FFT rounds 1-3 register-resident via __shfl_xor lane<->reg transposes
//    (v11: removed 2 barriers + 64 LDS ops/thread; kernel 111 -> <99 us).
//  - Mag phase now single-pass read-compute-write with NO staging barriers:
//    race-free by slot ownership -- thread computing k in [1..1024] writes
//    only sw(k), which only that thread reads; mirror reads hit sw(2048-k)
//    in [1024..2047], never written (k=1024 self-paired, read-before-write).
//    7 -> 6 barriers, one full LDS pass deleted.
//  - Everything else byte-identical to v11/R4: pair rFFT, register-carried
//    seq, wave-register top-5, shifted-f4 + regular f4 store phase.
// ---------------------------------------------------------------------------
__global__ __launch_bounds__(256, 7) void pt_fft_tiles(const float* __restrict__ x,
                                                       float* __restrict__ out,
                                                       const float2* __restrict__ tw) {
    __shared__ __align__(16) float re[2052];   // FFT re / mags A / seq A (+4 slack)
    __shared__ __align__(16) float im[2052];   // FFT im / mags B / seq B (+4 slack)
    __shared__ int sh_take[2][K_];

    // XCD-aware swizzle: blocks with equal (blockIdx & 7) (likely same XCD)
    // get consecutive q -> adjacent x columns -> L2 line reuse.
    const int i0  = blockIdx.x;
    const int q   = ((i0 & 7) << 8) | (i0 >> 3);
    const int bn0 = q * 2;
    const int b   = bn0 >> 7;          // / N_
    const int n   = bn0 & 127;         // even
    const int tid = threadIdx.x;

    // ---- Load x columns (n, n+1): bit-reversed pack into re/im.
    // v[] stays live in registers until the store phase (no reload, no seq LDS).
    const float* xp = x + (size_t)b * T_ * N_ + n;
    float2 v[8];
#pragma unroll
    for (int m = 0; m < 8; ++m)
        v[m] = *(const float2*)(xp + (size_t)(tid + 256 * m) * N_);
#pragma unroll
    for (int m = 0; m < 8; ++m) {
        const int t = tid + 256 * m;
        const int p = sw((int)(__brev((unsigned)t) >> 21));   // pos = rev11(t)
        re[p] = v[m].x;
        im[p] = v[m].y;
    }
    __syncthreads();

    // ================= FFT rounds 1-3, register-resident =================
    cf E[8];

    // ---- Round 1: radix-8 (stages 1-3), h=1, constant twiddles.
    {
        const int base = tid * 8;
#pragma unroll
        for (int j = 0; j < 8; ++j) { const int p = sw(base + j); E[j].r = re[p]; E[j].i = im[p]; }
        bf_1(E[0], E[1]); bf_1(E[2], E[3]); bf_1(E[4], E[5]); bf_1(E[6], E[7]);
        bf_1(E[0], E[2]); bf_mi(E[1], E[3]); bf_1(E[4], E[6]); bf_mi(E[5], E[7]);
        bf_1(E[0], E[4]); bf_w(E[1], E[5], S2_F, -S2_F);
        bf_mi(E[2], E[6]); bf_w(E[3], E[7], -S2_F, -S2_F);
    }

    // ---- Exchange 1 (intra-wave, 8-lane groups): lane[2:0] <-> reg[2:0].
    XSTAGE(1, 0,1, 2,3, 4,5, 6,7)      // lane bit0 <-> reg bit0
    XSTAGE(2, 0,2, 1,3, 4,6, 5,7)      // lane bit1 <-> reg bit1
    XSTAGE(4, 0,4, 1,5, 2,6, 3,7)      // lane bit2 <-> reg bit2

    // ---- Round 2: radix-8 at stage s=4 (h=8), twiddles as R4.
    {
        const int bq = tid & 7;
        const float2 w1  = tw[bq << 7];
        const float2 w2a = tw[bq << 6];
        const float2 w2b = tw[(bq + 8) << 6];
        const float2 w30 = tw[bq << 5];
        const float2 w31 = tw[(bq + 8) << 5];
        const float2 w32 = tw[(bq + 16) << 5];
        const float2 w33 = tw[(bq + 24) << 5];
        bf_w(E[0], E[1], w1.x, w1.y);   bf_w(E[2], E[3], w1.x, w1.y);
        bf_w(E[4], E[5], w1.x, w1.y);   bf_w(E[6], E[7], w1.x, w1.y);
        bf_w(E[0], E[2], w2a.x, w2a.y); bf_w(E[1], E[3], w2b.x, w2b.y);
        bf_w(E[4], E[6], w2a.x, w2a.y); bf_w(E[5], E[7], w2b.x, w2b.y);
        bf_w(E[0], E[4], w30.x, w30.y); bf_w(E[1], E[5], w31.x, w31.y);
        bf_w(E[2], E[6], w32.x, w32.y); bf_w(E[3], E[7], w33.x, w33.y);
    }

    // ---- Exchange 2 (intra-wave, 64-lane): lane[5:3] <-> reg[2:0].
    XSTAGE(8,  0,1, 2,3, 4,5, 6,7)     // lane bit3 <-> reg bit0
    XSTAGE(16, 0,2, 1,3, 4,6, 5,7)     // lane bit4 <-> reg bit1
    XSTAGE(32, 0,4, 1,5, 2,6, 3,7)     // lane bit5 <-> reg bit2

    // ---- Round 3: radix-8 at stage s=7 (h=64), twiddles as R4; write back
    // to the exact sw() positions R4's round 3 produced.
    {
        const int bq = tid & 63;
        const float2 w1  = tw[bq << 4];
        const float2 w2a = tw[bq << 3];
        const float2 w2b = tw[(bq + 64) << 3];
        const float2 w30 = tw[bq << 2];
        const float2 w31 = tw[(bq + 64) << 2];
        const float2 w32 = tw[(bq + 128) << 2];
        const float2 w33 = tw[(bq + 192) << 2];
        bf_w(E[0], E[1], w1.x, w1.y);   bf_w(E[2], E[3], w1.x, w1.y);
        bf_w(E[4], E[5], w1.x, w1.y);   bf_w(E[6], E[7], w1.x, w1.y);
        bf_w(E[0], E[2], w2a.x, w2a.y); bf_w(E[1], E[3], w2b.x, w2b.y);
        bf_w(E[4], E[6], w2a.x, w2a.y); bf_w(E[5], E[7], w2b.x, w2b.y);
        bf_w(E[0], E[4], w30.x, w30.y); bf_w(E[1], E[5], w31.x, w31.y);
        bf_w(E[2], E[6], w32.x, w32.y); bf_w(E[3], E[7], w33.x, w33.y);
        const int base = (tid >> 6) * 512 + (tid & 63);
#pragma unroll
        for (int j = 0; j < 8; ++j) { const int p = sw(base + j * 64); re[p] = E[j].r; im[p] = E[j].i; }
    }
    __syncthreads();
    // ================= end register-resident rounds =================

    // ---- Round 4: radix-4 (stages 10-11), h=512, 2 butterflies/thread.
#pragma unroll
    for (int u = 0; u < 2; ++u) {
        const int bb = tid + 256 * u;
        const float2 wA = tw[bb << 1];
        const float2 wB = tw[bb];
        const float2 wC = tw[bb + 512];
        const int p0 = sw(bb), p1 = sw(bb + 512), p2 = sw(bb + 1024), p3 = sw(bb + 1536);
        cf E0 = {re[p0], im[p0]}, E1 = {re[p1], im[p1]};
        cf E2 = {re[p2], im[p2]}, E3 = {re[p3], im[p3]};
        bf_w(E0, E1, wA.x, wA.y); bf_w(E2, E3, wA.x, wA.y);
        bf_w(E0, E2, wB.x, wB.y); bf_w(E1, E3, wC.x, wC.y);
        re[p0] = E0.r; im[p0] = E0.i; re[p1] = E1.r; im[p1] = E1.i;
        re[p2] = E2.r; im[p2] = E2.i; re[p3] = E3.r; im[p3] = E3.i;
    }
    __syncthreads();

    // ---- Unpack both spectra; 4*mag^2, FUSED single pass (no staging, no
    // extra barriers). Race-free by slot ownership: thread of k writes only
    // sw(k) (k in 1..1024), which only it reads; mirror reads sw(2048-k) in
    // [1024..2047] are never written (k=1024 self-paired, read-before-write).
#pragma unroll
    for (int m = 0; m < 4; ++m) {
        const int k  = 1 + tid + 256 * m;          // 1..1024
        const int nk = 2048 - k;
        const int pk = sw(k), pn = sw(nk);
        const float zr = re[pk], zi = im[pk];
        const float yr = re[pn], yi = im[pn];
        const float ar = zr + yr, ai = zi - yi;
        const float br = zi + yi, bi = yr - zr;
        re[pk] = ar * ar + ai * ai;
        im[pk] = br * br + bi * bi;
    }
    __syncthreads();

    // ---- Top-5, intra-wave + register-resident: wave0 -> A (re), wave1 -> B (im).
    const int wid  = tid >> 6;
    const int lane = tid & 63;
    if (wid < 2) {
        const float* marr = wid ? im : re;
        float mv[16];
#pragma unroll
        for (int j = 0; j < 16; ++j) mv[j] = marr[sw(1 + lane + 64 * j)];
        for (int it = 0; it < K_; ++it) {
            float bestv = -2.0f;
            int   besti = 1 << 30;
#pragma unroll
            for (int j = 0; j < 16; ++j) {
                const int k = 1 + lane + 64 * j;
                if (mv[j] > bestv || (mv[j] == bestv && k < besti)) { bestv = mv[j]; besti = k; }
            }
#pragma unroll
            for (int off = 32; off > 0; off >>= 1) {
                const float v3 = __shfl_down(bestv, off);
                const int   i3 = __shfl_down(besti, off);
                if (v3 > bestv || (v3 == bestv && i3 < besti)) { bestv = v3; besti = i3; }
            }
            const int win = __shfl(besti, 0);      // broadcast winner index
#pragma unroll
            for (int j = 0; j < 16; ++j)
                if (1 + lane + 64 * j == win) mv[j] = -1.0f;   // exclude
            if (lane == 0) {
                int period = T_ / win;
                if (period > PMAX_) period = PMAX_;
                if (period < MINP_) period = MINP_;
                const int cyc = T_ / period;
                sh_take[wid][it] = (period << 16) | (period * cyc); // pack period|take
            }
        }
    }
    __syncthreads();

    // ---- periods / cycles (ints as float32).
    const size_t TILES = (size_t)BN_ * K_ * T_;
    if (tid < 2 * K_) {
        const int s2 = tid / K_, k2 = tid % K_;
        const int pk   = sh_take[s2][k2];
        const int per  = pk >> 16;
        const int take = pk & 0xFFFF;
        out[TILES + (size_t)(bn0 + s2) * K_ + k2]                      = (float)per;
        out[TILES + (size_t)BN_ * K_ + (size_t)(bn0 + s2) * K_ + k2]   = (float)(take / per);
    }

    // ---- Restore sequences linearly into re (A) / im (B) FROM REGISTERS;
    // mags are dead after top-5. No global reload.
#pragma unroll
    for (int m = 0; m < 8; ++m) {
        const int t = tid + 256 * m;
        re[t] = v[m].x;
        im[t] = v[m].y;
    }
    __syncthreads();

    // ---- Tile rows: aligned f4 LDS reads + register shift, REGULAR aligned
    // float4 stores (same shape as the 6.5 TB/s fill kernel).
    float* rowA = out + (size_t)bn0 * (K_ * T_);
#pragma unroll
    for (int m = 0; m < 20; ++m) {
        const int e  = tid + 256 * m;
        const int s2 = (e >= K_ * (T_ / 4)) ? 1 : 0;
        const int w  = e - s2 * (K_ * (T_ / 4));
        const int k  = w >> 9;                     // / 512
        const int p4 = (w & 511) << 2;
        const int take  = sh_take[s2][k] & 0xFFFF;
        const int start = T_ - take;
        const vf4* sq4 = (const vf4*)(s2 ? im : re);
        const int idx = start + p4;
        int a0 = idx >> 2;
        if (a0 > 511) a0 = 511;                    // clamp (masked anyway)
        const int sh = idx & 3;
        const vf4 lo = sq4[a0];
        const vf4 hi = sq4[a0 + 1];
        float r0, r1, r2, r3;
        if (sh == 0)      { r0 = lo.x; r1 = lo.y; r2 = lo.z; r3 = lo.w; }
        else if (sh == 1) { r0 = lo.y; r1 = lo.z; r2 = lo.w; r3 = hi.x; }
        else if (sh == 2) { r0 = lo.z; r1 = lo.w; r2 = hi.x; r3 = hi.y; }
        else              { r0 = lo.w; r1 = hi.x; r2 = hi.y; r3 = hi.z; }
        vf4 vv;
        vv.x = (p4 + 0 < take) ? r0 : 0.0f;
        vv.y = (p4 + 1 < take) ? r1 : 0.0f;
        vv.z = (p4 + 2 < take) ? r2 : 0.0f;
        vv.w = (p4 + 3 < take) ? r3 : 0.0f;
        *(vf4*)(rowA + (size_t)(s2 * K_ + k) * T_ + p4) = vv;
    }
}

// ---------------------------------------------------------------------------
extern "C" void kernel_launch(void* const* d_in, const int* in_sizes, int n_in,
                              void* d_out, int out_size, void* d_ws, size_t ws_size,
                              hipStream_t stream) {
    const float* x = (const float*)d_in[0];
    float* out = (float*)d_out;
    float2* tw = (float2*)d_ws;   // 8 KB twiddle table

    pt_twiddle<<<dim3(4), dim3(256), 0, stream>>>(tw);
    pt_fft_tiles<<<dim3(BN_ / 2), dim3(256), 0, stream>>>(x, out, tw);
}

// Round 13
// 209.400 us; speedup vs baseline: 1.0287x; 1.0287x over previous
//
#include <hip/hip_runtime.h>

#define B_ 32
#define T_ 2048
#define N_ 128
#define K_ 5
#define BN_ (B_ * N_)
#define PMAX_ 512
#define MINP_ 2

static constexpr double PI_D = 3.14159265358979323846264338327950288;
static constexpr float  S2_F = 0.70710678118654752440f;  // sqrt(1/2)

typedef float vf4 __attribute__((ext_vector_type(4)));

struct cf { float r, i; };

__device__ __forceinline__ void bf_w(cf& u, cf& v, float wr, float wi) {
    const float tr = v.r * wr - v.i * wi;
    const float ti = v.r * wi + v.i * wr;
    v.r = u.r - tr; v.i = u.i - ti;
    u.r += tr;      u.i += ti;
}
__device__ __forceinline__ void bf_1(cf& u, cf& v) {        // w = 1
    const float tr = v.r, ti = v.i;
    v.r = u.r - tr; v.i = u.i - ti;
    u.r += tr;      u.i += ti;
}
__device__ __forceinline__ void bf_mi(cf& u, cf& v) {       // w = -i
    const float tr = v.i, ti = -v.r;
    v.r = u.r - tr; v.i = u.i - ti;
    u.r += tr;      u.i += ti;
}
// LDS bank swizzle: keeps every hot access pattern low-way on 32 banks.
__device__ __forceinline__ int sw(int i) { return i ^ ((i >> 5) & 31); }

// Swap lane-bit L with one reg-bit across a register pair (a=low, b=high).
__device__ __forceinline__ void xsw1(float& a, float& b, int tid, int L) {
    const float snd = (tid & L) ? a : b;
    const float got = __shfl_xor(snd, L, 64);
    if (tid & L) a = got; else b = got;
}
// One full stage: swap lane-bit L with reg-bit R over cf E[8] (re & im).
#define XSTAGE(L, P0a, P0b, P1a, P1b, P2a, P2b, P3a, P3b)                      \
    xsw1(E[P0a].r, E[P0b].r, tid, (L)); xsw1(E[P0a].i, E[P0b].i, tid, (L));    \
    xsw1(E[P1a].r, E[P1b].r, tid, (L)); xsw1(E[P1a].i, E[P1b].i, tid, (L));    \
    xsw1(E[P2a].r, E[P2b].r, tid, (L)); xsw1(E[P2a].i, E[P2b].i, tid, (L));    \
    xsw1(E[P3a].r, E[P3b].r, tid, (L)); xsw1(E[P3a].i, E[P3b].i, tid, (L));

// ---------------------------------------------------------------------------
// Kernel 0: twiddle table tw[m] = exp(-2*pi*i*m/2048) as float2, into d_ws.
// ---------------------------------------------------------------------------
__global__ __launch_bounds__(256) void pt_twiddle(float2* __restrict__ tw) {
    const int m = blockIdx.x * 256 + threadIdx.x;
    if (m < 1024) {
        double s, c;
        sincos(-2.0 * PI_D * (double)m / 2048.0, &s, &c);
        tw[m] = make_float2((float)c, (float)s);
    }
}

// ---------------------------------------------------------------------------
// v13 = v12 + bit-reversal folded into GLOBAL LOAD addressing:
//  - Round 1 needs E[j] = A[8*tid+j] = x[256*rev3(j) + rev8(tid)]
//    (rev11(8t+j): j bits 2:0 -> 10:8, t bits 10:3 -> 7:0). Load those rows
//    directly into registers: the LDS pack phase, its barrier, and round 1's
//    LDS reads are DELETED (6 -> 5 barriers, -32 LDS ops/thread).
//    Same per-lane 512B-stride profile -> FETCH/L2 sharing unchanged.
//  - Seq restore writes v[j] to its true linear slot 256*rev3(j)+rev8(tid)
//    (8-way bank conflicts on 16 writes: far cheaper than the deleted pass).
//  - FFT rounds 1-3 register-resident via __shfl_xor transposes (v11),
//    fused single-pass mag (v12), wave-register top-5, shifted-f4 store
//    phase -- all byte-identical to the session-best path.
// ---------------------------------------------------------------------------
__global__ __launch_bounds__(256, 7) void pt_fft_tiles(const float* __restrict__ x,
                                                       float* __restrict__ out,
                                                       const float2* __restrict__ tw) {
    __shared__ __align__(16) float re[2052];   // FFT re / mags A / seq A (+4 slack)
    __shared__ __align__(16) float im[2052];   // FFT im / mags B / seq B (+4 slack)
    __shared__ int sh_take[2][K_];

    // XCD-aware swizzle: blocks with equal (blockIdx & 7) (likely same XCD)
    // get consecutive q -> adjacent x columns -> L2 line reuse.
    const int i0  = blockIdx.x;
    const int q   = ((i0 & 7) << 8) | (i0 >> 3);
    const int bn0 = q * 2;
    const int b   = bn0 >> 7;          // / N_
    const int n   = bn0 & 127;         // even
    const int tid = threadIdx.x;

    // ---- Load x columns (n, n+1) DIRECTLY in bit-reversed order:
    // v[j] = x[row j] with row = 256*rev3(j) + rev8(tid), so E[j] = A[8*tid+j]
    // without any LDS pack. v[] stays live until the store phase.
    const float* xp = x + (size_t)b * T_ * N_ + n;
    const int r8 = (int)(__brev((unsigned)tid) >> 24);        // rev8(tid)
    // 256*rev3(j) for j=0..7: {0,1024,512,1536,256,1280,768,1792}
    float2 v[8];
    v[0] = *(const float2*)(xp + (size_t)(r8 +    0) * N_);
    v[1] = *(const float2*)(xp + (size_t)(r8 + 1024) * N_);
    v[2] = *(const float2*)(xp + (size_t)(r8 +  512) * N_);
    v[3] = *(const float2*)(xp + (size_t)(r8 + 1536) * N_);
    v[4] = *(const float2*)(xp + (size_t)(r8 +  256) * N_);
    v[5] = *(const float2*)(xp + (size_t)(r8 + 1280) * N_);
    v[6] = *(const float2*)(xp + (size_t)(r8 +  768) * N_);
    v[7] = *(const float2*)(xp + (size_t)(r8 + 1792) * N_);

    // ================= FFT rounds 1-3, register-resident =================
    cf E[8];
#pragma unroll
    for (int j = 0; j < 8; ++j) { E[j].r = v[j].x; E[j].i = v[j].y; }

    // ---- Round 1: radix-8 (stages 1-3), h=1, constant twiddles.
    bf_1(E[0], E[1]); bf_1(E[2], E[3]); bf_1(E[4], E[5]); bf_1(E[6], E[7]);
    bf_1(E[0], E[2]); bf_mi(E[1], E[3]); bf_1(E[4], E[6]); bf_mi(E[5], E[7]);
    bf_1(E[0], E[4]); bf_w(E[1], E[5], S2_F, -S2_F);
    bf_mi(E[2], E[6]); bf_w(E[3], E[7], -S2_F, -S2_F);

    // ---- Exchange 1 (intra-wave, 8-lane groups): lane[2:0] <-> reg[2:0].
    XSTAGE(1, 0,1, 2,3, 4,5, 6,7)      // lane bit0 <-> reg bit0
    XSTAGE(2, 0,2, 1,3, 4,6, 5,7)      // lane bit1 <-> reg bit1
    XSTAGE(4, 0,4, 1,5, 2,6, 3,7)      // lane bit2 <-> reg bit2

    // ---- Round 2: radix-8 at stage s=4 (h=8).
    {
        const int bq = tid & 7;
        const float2 w1  = tw[bq << 7];
        const float2 w2a = tw[bq << 6];
        const float2 w2b = tw[(bq + 8) << 6];
        const float2 w30 = tw[bq << 5];
        const float2 w31 = tw[(bq + 8) << 5];
        const float2 w32 = tw[(bq + 16) << 5];
        const float2 w33 = tw[(bq + 24) << 5];
        bf_w(E[0], E[1], w1.x, w1.y);   bf_w(E[2], E[3], w1.x, w1.y);
        bf_w(E[4], E[5], w1.x, w1.y);   bf_w(E[6], E[7], w1.x, w1.y);
        bf_w(E[0], E[2], w2a.x, w2a.y); bf_w(E[1], E[3], w2b.x, w2b.y);
        bf_w(E[4], E[6], w2a.x, w2a.y); bf_w(E[5], E[7], w2b.x, w2b.y);
        bf_w(E[0], E[4], w30.x, w30.y); bf_w(E[1], E[5], w31.x, w31.y);
        bf_w(E[2], E[6], w32.x, w32.y); bf_w(E[3], E[7], w33.x, w33.y);
    }

    // ---- Exchange 2 (intra-wave, 64-lane): lane[5:3] <-> reg[2:0].
    XSTAGE(8,  0,1, 2,3, 4,5, 6,7)     // lane bit3 <-> reg bit0
    XSTAGE(16, 0,2, 1,3, 4,6, 5,7)     // lane bit4 <-> reg bit1
    XSTAGE(32, 0,4, 1,5, 2,6, 3,7)     // lane bit5 <-> reg bit2

    // ---- Round 3: radix-8 at stage s=7 (h=64); write back to LDS at the
    // same sw() positions the R4 lineage produced.
    {
        const int bq = tid & 63;
        const float2 w1  = tw[bq << 4];
        const float2 w2a = tw[bq << 3];
        const float2 w2b = tw[(bq + 64) << 3];
        const float2 w30 = tw[bq << 2];
        const float2 w31 = tw[(bq + 64) << 2];
        const float2 w32 = tw[(bq + 128) << 2];
        const float2 w33 = tw[(bq + 192) << 2];
        bf_w(E[0], E[1], w1.x, w1.y);   bf_w(E[2], E[3], w1.x, w1.y);
        bf_w(E[4], E[5], w1.x, w1.y);   bf_w(E[6], E[7], w1.x, w1.y);
        bf_w(E[0], E[2], w2a.x, w2a.y); bf_w(E[1], E[3], w2b.x, w2b.y);
        bf_w(E[4], E[6], w2a.x, w2a.y); bf_w(E[5], E[7], w2b.x, w2b.y);
        bf_w(E[0], E[4], w30.x, w30.y); bf_w(E[1], E[5], w31.x, w31.y);
        bf_w(E[2], E[6], w32.x, w32.y); bf_w(E[3], E[7], w33.x, w33.y);
        const int base = (tid >> 6) * 512 + (tid & 63);
#pragma unroll
        for (int j = 0; j < 8; ++j) { const int p = sw(base + j * 64); re[p] = E[j].r; im[p] = E[j].i; }
    }
    __syncthreads();
    // ================= end register-resident rounds =================

    // ---- Round 4: radix-4 (stages 10-11), h=512, 2 butterflies/thread.
#pragma unroll
    for (int u = 0; u < 2; ++u) {
        const int bb = tid + 256 * u;
        const float2 wA = tw[bb << 1];
        const float2 wB = tw[bb];
        const float2 wC = tw[bb + 512];
        const int p0 = sw(bb), p1 = sw(bb + 512), p2 = sw(bb + 1024), p3 = sw(bb + 1536);
        cf E0 = {re[p0], im[p0]}, E1 = {re[p1], im[p1]};
        cf E2 = {re[p2], im[p2]}, E3 = {re[p3], im[p3]};
        bf_w(E0, E1, wA.x, wA.y); bf_w(E2, E3, wA.x, wA.y);
        bf_w(E0, E2, wB.x, wB.y); bf_w(E1, E3, wC.x, wC.y);
        re[p0] = E0.r; im[p0] = E0.i; re[p1] = E1.r; im[p1] = E1.i;
        re[p2] = E2.r; im[p2] = E2.i; re[p3] = E3.r; im[p3] = E3.i;
    }
    __syncthreads();

    // ---- Unpack both spectra; 4*mag^2, FUSED single pass (race-free by
    // slot ownership: thread of k writes only sw(k), which only it reads;
    // mirror reads sw(2048-k) in [1024..2047] are never written).
#pragma unroll
    for (int m = 0; m < 4; ++m) {
        const int k  = 1 + tid + 256 * m;          // 1..1024
        const int nk = 2048 - k;
        const int pk = sw(k), pn = sw(nk);
        const float zr = re[pk], zi = im[pk];
        const float yr = re[pn], yi = im[pn];
        const float ar = zr + yr, ai = zi - yi;
        const float br = zi + yi, bi = yr - zr;
        re[pk] = ar * ar + ai * ai;
        im[pk] = br * br + bi * bi;
    }
    __syncthreads();

    // ---- Top-5, intra-wave + register-resident: wave0 -> A (re), wave1 -> B (im).
    const int wid  = tid >> 6;
    const int lane = tid & 63;
    if (wid < 2) {
        const float* marr = wid ? im : re;
        float mv[16];
#pragma unroll
        for (int j = 0; j < 16; ++j) mv[j] = marr[sw(1 + lane + 64 * j)];
        for (int it = 0; it < K_; ++it) {
            float bestv = -2.0f;
            int   besti = 1 << 30;
#pragma unroll
            for (int j = 0; j < 16; ++j) {
                const int k = 1 + lane + 64 * j;
                if (mv[j] > bestv || (mv[j] == bestv && k < besti)) { bestv = mv[j]; besti = k; }
            }
#pragma unroll
            for (int off = 32; off > 0; off >>= 1) {
                const float v3 = __shfl_down(bestv, off);
                const int   i3 = __shfl_down(besti, off);
                if (v3 > bestv || (v3 == bestv && i3 < besti)) { bestv = v3; besti = i3; }
            }
            const int win = __shfl(besti, 0);      // broadcast winner index
#pragma unroll
            for (int j = 0; j < 16; ++j)
                if (1 + lane + 64 * j == win) mv[j] = -1.0f;   // exclude
            if (lane == 0) {
                int period = T_ / win;
                if (period > PMAX_) period = PMAX_;
                if (period < MINP_) period = MINP_;
                const int cyc = T_ / period;
                sh_take[wid][it] = (period << 16) | (period * cyc); // pack period|take
            }
        }
    }
    __syncthreads();

    // ---- periods / cycles (ints as float32).
    const size_t TILES = (size_t)BN_ * K_ * T_;
    if (tid < 2 * K_) {
        const int s2 = tid / K_, k2 = tid % K_;
        const int pk   = sh_take[s2][k2];
        const int per  = pk >> 16;
        const int take = pk & 0xFFFF;
        out[TILES + (size_t)(bn0 + s2) * K_ + k2]                      = (float)per;
        out[TILES + (size_t)BN_ * K_ + (size_t)(bn0 + s2) * K_ + k2]   = (float)(take / per);
    }

    // ---- Restore sequences into re (A) / im (B) FROM REGISTERS at their
    // true linear slots: v[j] holds x[256*rev3(j) + rev8(tid)].
#pragma unroll
    for (int j = 0; j < 8; ++j) {
        static const int roff[8] = {0, 1024, 512, 1536, 256, 1280, 768, 1792};
        const int t = r8 + roff[j];
        re[t] = v[j].x;
        im[t] = v[j].y;
    }
    __syncthreads();

    // ---- Tile rows: aligned f4 LDS reads + register shift, REGULAR aligned
    // float4 stores (same shape as the 6.5 TB/s fill kernel).
    float* rowA = out + (size_t)bn0 * (K_ * T_);
#pragma unroll
    for (int m = 0; m < 20; ++m) {
        const int e  = tid + 256 * m;
        const int s2 = (e >= K_ * (T_ / 4)) ? 1 : 0;
        const int w  = e - s2 * (K_ * (T_ / 4));
        const int k  = w >> 9;                     // / 512
        const int p4 = (w & 511) << 2;
        const int take  = sh_take[s2][k] & 0xFFFF;
        const int start = T_ - take;
        const vf4* sq4 = (const vf4*)(s2 ? im : re);
        const int idx = start + p4;
        int a0 = idx >> 2;
        if (a0 > 511) a0 = 511;                    // clamp (masked anyway)
        const int sh = idx & 3;
        const vf4 lo = sq4[a0];
        const vf4 hi = sq4[a0 + 1];
        float r0, r1, r2, r3;
        if (sh == 0)      { r0 = lo.x; r1 = lo.y; r2 = lo.z; r3 = lo.w; }
        else if (sh == 1) { r0 = lo.y; r1 = lo.z; r2 = lo.w; r3 = hi.x; }
        else if (sh == 2) { r0 = lo.z; r1 = lo.w; r2 = hi.x; r3 = hi.y; }
        else              { r0 = lo.w; r1 = hi.x; r2 = hi.y; r3 = hi.z; }
        vf4 vv;
        vv.x = (p4 + 0 < take) ? r0 : 0.0f;
        vv.y = (p4 + 1 < take) ? r1 : 0.0f;
        vv.z = (p4 + 2 < take) ? r2 : 0.0f;
        vv.w = (p4 + 3 < take) ? r3 : 0.0f;
        *(vf4*)(rowA + (size_t)(s2 * K_ + k) * T_ + p4) = vv;
    }
}

// ---------------------------------------------------------------------------
extern "C" void kernel_launch(void* const* d_in, const int* in_sizes, int n_in,
                              void* d_out, int out_size, void* d_ws, size_t ws_size,
                              hipStream_t stream) {
    const float* x = (const float*)d_in[0];
    float* out = (float*)d_out;
    float2* tw = (float2*)d_ws;   // 8 KB twiddle table

    pt_twiddle<<<dim3(4), dim3(256), 0, stream>>>(tw);
    pt_fft_tiles<<<dim3(BN_ / 2), dim3(256), 0, stream>>>(x, out, tw);
}